// Round 1
// baseline (273.429 us; speedup 1.0000x reference)
//
#include <hip/hip_runtime.h>

#define BATCH 16
#define NN    256
#define E     128
#define DNODE 5
#define TJ    16

// ---------- helpers ----------
__device__ inline float blk_reduce_128(float v, float* red) {
    // 128 threads = 2 waves of 64
    #pragma unroll
    for (int off = 32; off > 0; off >>= 1) v += __shfl_down(v, off, 64);
    int lane = threadIdx.x & 63, wv = threadIdx.x >> 6;
    if (lane == 0) red[wv] = v;
    __syncthreads();
    return red[0] + red[1];
}

// ---------- s1 = relu(xv@t1_w + t1_b) @ layer_w + layer_b ----------
__global__ void k_s1(const float* __restrict__ xv, const float* __restrict__ t1w,
                     const float* __restrict__ t1b, const float* __restrict__ lw,
                     const float* __restrict__ lb, float* __restrict__ s1) {
    int r = blockIdx.x;      // b*NN + n
    int e = threadIdx.x;     // 0..127
    __shared__ float h[E];
    float x0 = xv[r*DNODE+0], x1 = xv[r*DNODE+1], x2 = xv[r*DNODE+2],
          x3 = xv[r*DNODE+3], x4 = xv[r*DNODE+4];
    float acc = t1b[e];
    acc += x0*t1w[0*E+e] + x1*t1w[1*E+e] + x2*t1w[2*E+e]
         + x3*t1w[3*E+e] + x4*t1w[4*E+e];
    h[e] = fmaxf(acc, 0.f);
    __syncthreads();
    float s = lb[e];
    #pragma unroll 8
    for (int k = 0; k < E; ++k) s += h[k]*lw[k*E+e];
    s1[r*E+e] = s;
}

// ---------- s3 + sum13 + first-iteration mu ----------
// s3pre[b,j,e] = sum_i relu(Ws[b,i,j]*t4_w[e] + t4_b[e])
// s3 = s3pre @ t3_w + t3_b ;  sum13 = s1 + s3 ;  mu = relu(sum13 + t2_b)
__global__ void k_s3(const float* __restrict__ Ws, const float* __restrict__ t4w,
                     const float* __restrict__ t4b, const float* __restrict__ t3w,
                     const float* __restrict__ t3b, const float* __restrict__ t2b,
                     const float* __restrict__ s1,
                     float* __restrict__ sum13, float* __restrict__ mu) {
    int bj = blockIdx.x;           // b*NN + j
    int b = bj >> 8, j = bj & 255;
    int e = threadIdx.x;
    __shared__ float wcol[NN];
    __shared__ float spre[E];
    wcol[e]       = Ws[(b*NN + e)*NN + j];
    wcol[e + 128] = Ws[(b*NN + e + 128)*NN + j];
    __syncthreads();
    float w4 = t4w[e], b4 = t4b[e];
    float acc = 0.f;
    #pragma unroll 8
    for (int i = 0; i < NN; ++i) acc += fmaxf(wcol[i]*w4 + b4, 0.f);
    spre[e] = acc;
    __syncthreads();
    float s = t3b[e];
    #pragma unroll 8
    for (int k = 0; k < E; ++k) s += spre[k]*t3w[k*E+e];
    float v = s1[bj*E+e] + s;
    sum13[bj*E+e] = v;
    // first message-passing iteration: mu0 = 0 -> s2 = t2_b exactly
    mu[bj*E+e] = fmaxf(v + t2b[e], 0.f);
}

// ---------- C[b,j,:] = sum_i conn[b,j,i] * mu[b,i,:] ----------
__global__ void k_connmm(const float* __restrict__ Ws, const float* __restrict__ mu,
                         float* __restrict__ C) {
    int b  = blockIdx.x >> 4;          // 16 j-tiles per batch
    int j0 = (blockIdx.x & 15) * TJ;
    int e  = threadIdx.x;
    __shared__ float conn[TJ][NN];
    for (int idx = threadIdx.x; idx < TJ*NN; idx += 128) {
        int jj = idx >> 8, i = idx & 255;
        conn[jj][i] = (Ws[(b*NN + j0 + jj)*NN + i] > 0.f) ? 1.f : 0.f;
    }
    __syncthreads();
    float acc[TJ];
    #pragma unroll
    for (int jj = 0; jj < TJ; ++jj) acc[jj] = 0.f;
    for (int i = 0; i < NN; ++i) {
        float mv = mu[(b*NN + i)*E + e];
        #pragma unroll
        for (int jj = 0; jj < TJ; ++jj) acc[jj] += conn[jj][i]*mv;
    }
    #pragma unroll
    for (int jj = 0; jj < TJ; ++jj) C[(b*NN + j0 + jj)*E + e] = acc[jj];
}

// ---------- mu = relu(sum13 + C@t2_w + t2_b) ----------
__global__ void k_update(const float* __restrict__ C, const float* __restrict__ t2w,
                         const float* __restrict__ t2b, const float* __restrict__ sum13,
                         float* __restrict__ mu) {
    int r = blockIdx.x;
    int e = threadIdx.x;
    __shared__ float crow[E];
    crow[e] = C[r*E+e];
    __syncthreads();
    float acc = t2b[e] + sum13[r*E+e];
    #pragma unroll 8
    for (int k = 0; k < E; ++k) acc += crow[k]*t2w[k*E+e];
    mu[r*E+e] = fmaxf(acc, 0.f);
}

// ---------- gsum[b] = sum_e relu((sum_n mu)@t6_w + t6_b)[e] * t5_w[e] ----------
__global__ void k_global(const float* __restrict__ mu, const float* __restrict__ t6w,
                         const float* __restrict__ t6b, const float* __restrict__ t5w,
                         float* __restrict__ gsum) {
    int b = blockIdx.x;
    int e = threadIdx.x;
    __shared__ float pool[E];
    __shared__ float red[2];
    float acc = 0.f;
    for (int n = 0; n < NN; ++n) acc += mu[(b*NN+n)*E + e];
    pool[e] = acc;
    __syncthreads();
    float g = t6b[e];
    #pragma unroll 8
    for (int k = 0; k < E; ++k) g += pool[k]*t6w[k*E+e];
    float v = fmaxf(g, 0.f) * t5w[e];
    float tot = blk_reduce_128(v, red);
    if (e == 0) gsum[b] = tot;
}

// ---------- out[b,n] = gsum[b] + sum_e relu(mu@t7_w + t7_b)[e]*t5_w[128+e] + t5_b ----------
__global__ void k_out(const float* __restrict__ mu, const float* __restrict__ t7w,
                      const float* __restrict__ t7b, const float* __restrict__ t5w,
                      const float* __restrict__ t5b, const float* __restrict__ gsum,
                      float* __restrict__ out) {
    int r = blockIdx.x;
    int b = r >> 8;
    int e = threadIdx.x;
    __shared__ float murow[E];
    __shared__ float red[2];
    murow[e] = mu[r*E+e];
    __syncthreads();
    float la = t7b[e];
    #pragma unroll 8
    for (int k = 0; k < E; ++k) la += murow[k]*t7w[k*E+e];
    float v = fmaxf(la, 0.f) * t5w[E+e];
    float tot = blk_reduce_128(v, red);
    if (e == 0) out[r] = tot + gsum[b] + t5b[0];
}

extern "C" void kernel_launch(void* const* d_in, const int* in_sizes, int n_in,
                              void* d_out, int out_size, void* d_ws, size_t ws_size,
                              hipStream_t stream) {
    const float* xv  = (const float*)d_in[0];
    const float* Ws  = (const float*)d_in[1];
    const float* t1w = (const float*)d_in[2];  const float* t1b = (const float*)d_in[3];
    const float* t2w = (const float*)d_in[4];  const float* t2b = (const float*)d_in[5];
    const float* t3w = (const float*)d_in[6];  const float* t3b = (const float*)d_in[7];
    const float* t4w = (const float*)d_in[8];  const float* t4b = (const float*)d_in[9];
    const float* t5w = (const float*)d_in[10]; const float* t5b = (const float*)d_in[11];
    const float* t6w = (const float*)d_in[12]; const float* t6b = (const float*)d_in[13];
    const float* t7w = (const float*)d_in[14]; const float* t7b = (const float*)d_in[15];
    const float* lw  = (const float*)d_in[16]; const float* lb  = (const float*)d_in[17];
    float* out = (float*)d_out;

    float* ws = (float*)d_ws;
    const int RE = BATCH*NN*E;       // 524288 floats
    float* s1    = ws;               // dead after k_s3; reused as C
    float* C     = ws;
    float* sum13 = ws + RE;
    float* mu    = ws + 2*RE;
    float* gsum  = ws + 3*RE;        // 16 floats

    k_s1<<<BATCH*NN, E, 0, stream>>>(xv, t1w, t1b, lw, lb, s1);
    k_s3<<<BATCH*NN, E, 0, stream>>>(Ws, t4w, t4b, t3w, t3b, t2b, s1, sum13, mu);
    for (int t = 1; t < 4; ++t) {
        k_connmm<<<BATCH*16, E, 0, stream>>>(Ws, mu, C);
        k_update<<<BATCH*NN, E, 0, stream>>>(C, t2w, t2b, sum13, mu);
    }
    k_global<<<BATCH, E, 0, stream>>>(mu, t6w, t6b, t5w, gsum);
    k_out<<<BATCH*NN, E, 0, stream>>>(mu, t7w, t7b, t5w, t5b, gsum, out);
}

// Round 2
// 232.326 us; speedup vs baseline: 1.1769x; 1.1769x over previous
//
#include <hip/hip_runtime.h>

#define BATCH 16
#define NN    256
#define E     128
#define RT    8     // rows per block

typedef float f4 __attribute__((ext_vector_type(4)));

// ================= phase1: s1 + s3 + first-iteration mu =================
// s1  = relu(xv@t1w+t1b)@lw+lb
// s3  = (sum_i relu(Ws[b,i,j]*t4w+t4b)) @ t3w + t3b
// sum13 = s1+s3 ;  mu0 = relu(sum13 + t2b)   (mu_init=0 -> s2 == t2b)
__global__ __launch_bounds__(128) void k_phase1(
    const float* __restrict__ xv, const float* __restrict__ Ws,
    const float* __restrict__ t1w, const float* __restrict__ t1b,
    const float* __restrict__ t4w, const float* __restrict__ t4b,
    const float* __restrict__ t3w, const float* __restrict__ t3b,
    const float* __restrict__ lw,  const float* __restrict__ lb,
    const float* __restrict__ t2b,
    float* __restrict__ sum13, float* __restrict__ mu)
{
    const int b  = blockIdx.x >> 5;
    const int j0 = (blockIdx.x & 31) * RT;
    const int e  = threadIdx.x;
    __shared__ float wt[NN][RT];   // Ws[b][i][j0+jj]
    __shared__ float hsT[E][RT];   // relu(theta1) transposed: hsT[k][jj]
    __shared__ float spT[E][RT];   // s3pre transposed
    __shared__ float xs[RT][8];

    const float* wbase = Ws + (size_t)b*NN*NN;
    // stage Ws tile: 8 consecutive j per i (32B runs, L2-resident)
    #pragma unroll
    for (int p = 0; p < NN*RT/E; ++p) {
        int idx = e + p*E;
        int jj = idx & (RT-1), i = idx >> 3;
        wt[i][jj] = wbase[(size_t)i*NN + j0 + jj];
    }
    if (e < RT*5) {
        int jj = e / 5, d = e % 5;
        xs[jj][d] = xv[((size_t)(b*NN + j0 + jj))*5 + d];
    }
    __syncthreads();

    // theta1 + relu -> hsT
    {
        float b1 = t1b[e];
        float w0 = t1w[0*E+e], w1 = t1w[1*E+e], w2 = t1w[2*E+e],
              w3 = t1w[3*E+e], w4 = t1w[4*E+e];
        #pragma unroll
        for (int jj = 0; jj < RT; ++jj) {
            float h = b1 + xs[jj][0]*w0 + xs[jj][1]*w1 + xs[jj][2]*w2
                         + xs[jj][3]*w3 + xs[jj][4]*w4;
            hsT[e][jj] = fmaxf(h, 0.f);
        }
    }

    // s3pre: spre[jj][e] = sum_i relu(wt[i][jj]*t4w[e] + t4b[e])
    {
        float w4 = t4w[e], b4 = t4b[e];
        float acc[RT] = {0,0,0,0,0,0,0,0};
        #pragma unroll 4
        for (int i = 0; i < NN; ++i) {
            f4 a = *(const f4*)&wt[i][0];
            f4 c = *(const f4*)&wt[i][4];
            acc[0] += fmaxf(a.x*w4 + b4, 0.f);
            acc[1] += fmaxf(a.y*w4 + b4, 0.f);
            acc[2] += fmaxf(a.z*w4 + b4, 0.f);
            acc[3] += fmaxf(a.w*w4 + b4, 0.f);
            acc[4] += fmaxf(c.x*w4 + b4, 0.f);
            acc[5] += fmaxf(c.y*w4 + b4, 0.f);
            acc[6] += fmaxf(c.z*w4 + b4, 0.f);
            acc[7] += fmaxf(c.w*w4 + b4, 0.f);
        }
        #pragma unroll
        for (int jj = 0; jj < RT; ++jj) spT[e][jj] = acc[jj];
    }
    __syncthreads();

    // two 8x128x128 matmuls: s1 = hsT^T @ lw, s3 = spT^T @ t3w
    float s1a[RT], s3a[RT];
    {
        float lbe = lb[e], b3 = t3b[e];
        #pragma unroll
        for (int jj = 0; jj < RT; ++jj) { s1a[jj] = lbe; s3a[jj] = b3; }
        #pragma unroll 4
        for (int k = 0; k < E; ++k) {
            float w1 = lw[k*E+e];
            float w3 = t3w[k*E+e];
            f4 h0 = *(const f4*)&hsT[k][0];
            f4 h1 = *(const f4*)&hsT[k][4];
            f4 p0 = *(const f4*)&spT[k][0];
            f4 p1 = *(const f4*)&spT[k][4];
            s1a[0] += h0.x*w1; s1a[1] += h0.y*w1; s1a[2] += h0.z*w1; s1a[3] += h0.w*w1;
            s1a[4] += h1.x*w1; s1a[5] += h1.y*w1; s1a[6] += h1.z*w1; s1a[7] += h1.w*w1;
            s3a[0] += p0.x*w3; s3a[1] += p0.y*w3; s3a[2] += p0.z*w3; s3a[3] += p0.w*w3;
            s3a[4] += p1.x*w3; s3a[5] += p1.y*w3; s3a[6] += p1.z*w3; s3a[7] += p1.w*w3;
        }
    }
    float t2be = t2b[e];
    #pragma unroll
    for (int jj = 0; jj < RT; ++jj) {
        size_t off = ((size_t)(b*NN + j0 + jj))*E + e;
        float v = s1a[jj] + s3a[jj];
        sum13[off] = v;
        mu[off] = fmaxf(v + t2be, 0.f);
    }
}

// ================= iteration: mu_out = relu(sum13 + (conn@mu_in)@t2w + t2b) ==
__global__ __launch_bounds__(128) void k_iter(
    const float* __restrict__ Ws, const float* __restrict__ muin,
    const float* __restrict__ t2w, const float* __restrict__ t2b,
    const float* __restrict__ sum13, float* __restrict__ muout)
{
    const int b  = blockIdx.x >> 5;
    const int j0 = (blockIdx.x & 31) * RT;
    const int e  = threadIdx.x;
    __shared__ float cn[NN][RT];   // conn[b][j0+jj][i], transposed as [i][jj]
    __shared__ float ct[E][RT];    // C transposed: ct[k][jj]

    const float* wbase = Ws + (size_t)b*NN*NN;
    // conn rows j0..j0+7, coalesced over i
    #pragma unroll
    for (int p = 0; p < NN*RT/E; ++p) {
        int idx = e + p*E;
        int i = idx & (NN-1), jj = idx >> 8;
        cn[i][jj] = wbase[(size_t)(j0+jj)*NN + i] > 0.f ? 1.f : 0.f;
    }
    __syncthreads();

    // C[jj][e] = sum_i conn[jj][i] * mu[b,i,e]
    float acc[RT] = {0,0,0,0,0,0,0,0};
    const float* mb = muin + (size_t)b*NN*E + e;
    #pragma unroll 4
    for (int i = 0; i < NN; ++i) {
        float mv = mb[(size_t)i*E];
        f4 c0 = *(const f4*)&cn[i][0];
        f4 c1 = *(const f4*)&cn[i][4];
        acc[0] += c0.x*mv; acc[1] += c0.y*mv; acc[2] += c0.z*mv; acc[3] += c0.w*mv;
        acc[4] += c1.x*mv; acc[5] += c1.y*mv; acc[6] += c1.z*mv; acc[7] += c1.w*mv;
    }
    *(f4*)&ct[e][0] = (f4){acc[0],acc[1],acc[2],acc[3]};
    *(f4*)&ct[e][4] = (f4){acc[4],acc[5],acc[6],acc[7]};
    __syncthreads();

    // out[jj][e] = relu(sum13 + t2b[e] + sum_k C[jj][k]*t2w[k][e])
    float o[RT];
    float bb = t2b[e];
    #pragma unroll
    for (int jj = 0; jj < RT; ++jj) o[jj] = bb;
    #pragma unroll 4
    for (int k = 0; k < E; ++k) {
        float w = t2w[k*E+e];
        f4 c0 = *(const f4*)&ct[k][0];
        f4 c1 = *(const f4*)&ct[k][4];
        o[0] += c0.x*w; o[1] += c0.y*w; o[2] += c0.z*w; o[3] += c0.w*w;
        o[4] += c1.x*w; o[5] += c1.y*w; o[6] += c1.z*w; o[7] += c1.w*w;
    }
    #pragma unroll
    for (int jj = 0; jj < RT; ++jj) {
        size_t off = ((size_t)(b*NN + j0 + jj))*E + e;
        muout[off] = fmaxf(o[jj] + sum13[off], 0.f);
    }
}

// ================= global pooled branch ==================================
__global__ __launch_bounds__(128) void k_global(
    const float* __restrict__ mu, const float* __restrict__ t6w,
    const float* __restrict__ t6b, const float* __restrict__ t5w,
    float* __restrict__ gsum)
{
    int b = blockIdx.x;
    int e = threadIdx.x;
    __shared__ float pool[E];
    __shared__ float red[2];
    float acc = 0.f;
    const float* mb = mu + (size_t)b*NN*E + e;
    #pragma unroll 8
    for (int n = 0; n < NN; ++n) acc += mb[(size_t)n*E];
    pool[e] = acc;
    __syncthreads();
    float g = t6b[e];
    #pragma unroll 8
    for (int k = 0; k < E; ++k) g += pool[k]*t6w[k*E+e];
    float v = fmaxf(g, 0.f) * t5w[e];
    #pragma unroll
    for (int off = 32; off > 0; off >>= 1) v += __shfl_down(v, off, 64);
    if ((e & 63) == 0) red[e >> 6] = v;
    __syncthreads();
    if (e == 0) gsum[b] = red[0] + red[1];
}

// ================= output: theta7 + concat + theta5 ======================
__global__ __launch_bounds__(128) void k_out(
    const float* __restrict__ mu, const float* __restrict__ t7w,
    const float* __restrict__ t7b, const float* __restrict__ t5w,
    const float* __restrict__ t5b, const float* __restrict__ gsum,
    float* __restrict__ out)
{
    const int b  = blockIdx.x >> 5;
    const int j0 = (blockIdx.x & 31) * RT;
    const int e  = threadIdx.x;
    __shared__ float mT[E][RT];
    __shared__ float red[2][RT];
    #pragma unroll
    for (int p = 0; p < E*RT/E; ++p) {
        int idx = e + p*E;
        int k = idx & (E-1), jj = idx >> 7;
        mT[k][jj] = mu[((size_t)(b*NN + j0 + jj))*E + k];
    }
    __syncthreads();
    float o[RT];
    float b7 = t7b[e];
    #pragma unroll
    for (int jj = 0; jj < RT; ++jj) o[jj] = b7;
    #pragma unroll 4
    for (int k = 0; k < E; ++k) {
        float w = t7w[k*E+e];
        f4 m0 = *(const f4*)&mT[k][0];
        f4 m1 = *(const f4*)&mT[k][4];
        o[0] += m0.x*w; o[1] += m0.y*w; o[2] += m0.z*w; o[3] += m0.w*w;
        o[4] += m1.x*w; o[5] += m1.y*w; o[6] += m1.z*w; o[7] += m1.w*w;
    }
    float w5 = t5w[E + e];
    #pragma unroll
    for (int jj = 0; jj < RT; ++jj) {
        float v = fmaxf(o[jj], 0.f) * w5;
        #pragma unroll
        for (int off = 32; off > 0; off >>= 1) v += __shfl_down(v, off, 64);
        if ((e & 63) == 0) red[e >> 6][jj] = v;
    }
    __syncthreads();
    if (e < RT)
        out[(size_t)b*NN + j0 + e] = red[0][e] + red[1][e] + gsum[b] + t5b[0];
}

extern "C" void kernel_launch(void* const* d_in, const int* in_sizes, int n_in,
                              void* d_out, int out_size, void* d_ws, size_t ws_size,
                              hipStream_t stream) {
    const float* xv  = (const float*)d_in[0];
    const float* Ws  = (const float*)d_in[1];
    const float* t1w = (const float*)d_in[2];  const float* t1b = (const float*)d_in[3];
    const float* t2w = (const float*)d_in[4];  const float* t2b = (const float*)d_in[5];
    const float* t3w = (const float*)d_in[6];  const float* t3b = (const float*)d_in[7];
    const float* t4w = (const float*)d_in[8];  const float* t4b = (const float*)d_in[9];
    const float* t5w = (const float*)d_in[10]; const float* t5b = (const float*)d_in[11];
    const float* t6w = (const float*)d_in[12]; const float* t6b = (const float*)d_in[13];
    const float* t7w = (const float*)d_in[14]; const float* t7b = (const float*)d_in[15];
    const float* lw  = (const float*)d_in[16]; const float* lb  = (const float*)d_in[17];
    float* out = (float*)d_out;

    float* ws = (float*)d_ws;
    const int RE = BATCH*NN*E;
    float* sum13 = ws;
    float* mu0   = ws + RE;
    float* mu1   = ws + 2*RE;
    float* gsum  = ws + 3*RE;

    const int GRID = BATCH * (NN/RT);   // 512

    k_phase1<<<GRID, E, 0, stream>>>(xv, Ws, t1w, t1b, t4w, t4b, t3w, t3b,
                                     lw, lb, t2b, sum13, mu0);
    k_iter<<<GRID, E, 0, stream>>>(Ws, mu0, t2w, t2b, sum13, mu1);
    k_iter<<<GRID, E, 0, stream>>>(Ws, mu1, t2w, t2b, sum13, mu0);
    k_iter<<<GRID, E, 0, stream>>>(Ws, mu0, t2w, t2b, sum13, mu1);
    k_global<<<BATCH, E, 0, stream>>>(mu1, t6w, t6b, t5w, gsum);
    k_out<<<GRID, E, 0, stream>>>(mu1, t7w, t7b, t5w, t5b, gsum, out);
}

// Round 4
// 176.368 us; speedup vs baseline: 1.5503x; 1.3173x over previous
//
#include <hip/hip_runtime.h>

#define BATCH 16
#define NN    256
#define E     128
#define RT    4    // rows per block

typedef float f4 __attribute__((ext_vector_type(4)));

// Block = (batch b, rows j0..j0+3); 256 threads = (e in [0,128), h in {0,1}).
// h splits every serial reduction loop in half; partials combined via LDS.

// ============ phase1: s13 = s1+s3 ; mu0 = relu(s13 + t2b) ============
// (mu_init = 0  =>  s2 of iteration 1 == t2b exactly)
__global__ __launch_bounds__(256, 4) void k_phase1(
    const float* __restrict__ xv,  const float* __restrict__ Ws,
    const float* __restrict__ t1w, const float* __restrict__ t1b,
    const float* __restrict__ t4w, const float* __restrict__ t4b,
    const float* __restrict__ t3w, const float* __restrict__ t3b,
    const float* __restrict__ lw,  const float* __restrict__ lb,
    const float* __restrict__ t2b,
    float* __restrict__ s13g, float* __restrict__ mu0,
    float* __restrict__ poolbuf)
{
    const int blk = blockIdx.x;
    const int b   = blk >> 6;
    const int j0  = (blk & 63) * RT;
    const int t   = threadIdx.x;
    const int e   = t & (E-1);
    const int h   = t >> 7;

    __shared__ float sA[NN*RT];    // Ws col tile [i][jj]
    __shared__ float sB[RT*E];     // hsT [k][jj] -> then h1 partials [jj][e]
    __shared__ float sC[2*E*RT];   // s3pre partials [h][k][jj]

    const float* wbase = Ws + (size_t)b*NN*NN;

    if (blk < BATCH && h == 0) poolbuf[blk*E + e] = 0.f;

    // stage Ws column tile: sA[i][jj] = Ws[b,i,j0+jj]
    {
        f4 v = *(const f4*)(wbase + (size_t)t*NN + j0);
        *(f4*)(sA + t*4) = v;
    }
    if (h == 0) {   // theta1 + relu -> hsT[e][jj]
        float b1 = t1b[e];
        float w0=t1w[e], w1=t1w[E+e], w2=t1w[2*E+e], w3=t1w[3*E+e], w4=t1w[4*E+e];
        float hv[RT];
        #pragma unroll
        for (int jj = 0; jj < RT; ++jj) {
            const float* x = xv + (size_t)(b*NN + j0 + jj)*5;
            float s = b1 + x[0]*w0 + x[1]*w1 + x[2]*w2 + x[3]*w3 + x[4]*w4;
            hv[jj] = fmaxf(s, 0.f);
        }
        *(f4*)(sB + e*4) = (f4){hv[0],hv[1],hv[2],hv[3]};
    }
    __syncthreads();

    {   // s3pre partial over this thread's i-half
        float w4e = t4w[e], b4e = t4b[e];
        float a0=0,a1=0,a2=0,a3=0;
        const float* base = sA + h*128*4;
        #pragma unroll 4
        for (int i = 0; i < 128; ++i) {
            f4 c = *(const f4*)(base + i*4);   // broadcast read: conflict-free
            a0 += fmaxf(c.x*w4e + b4e, 0.f);
            a1 += fmaxf(c.y*w4e + b4e, 0.f);
            a2 += fmaxf(c.z*w4e + b4e, 0.f);
            a3 += fmaxf(c.w*w4e + b4e, 0.f);
        }
        *(f4*)(sC + (h*E + e)*4) = (f4){a0,a1,a2,a3};
    }
    __syncthreads();

    // (s1 + s3) partial over this thread's k-half
    float p0=0,p1=0,p2=0,p3=0;
    #pragma unroll 4
    for (int k = h*64; k < h*64+64; ++k) {
        float wl = lw[k*E+e], w3 = t3w[k*E+e];
        f4 hv = *(const f4*)(sB + k*4);
        f4 q0 = *(const f4*)(sC + k*4);
        f4 q1 = *(const f4*)(sC + (E+k)*4);
        p0 += hv.x*wl + (q0.x+q1.x)*w3;
        p1 += hv.y*wl + (q0.y+q1.y)*w3;
        p2 += hv.z*wl + (q0.z+q1.z)*w3;
        p3 += hv.w*wl + (q0.w+q1.w)*w3;
    }
    __syncthreads();
    if (h == 1) { sB[0*E+e]=p0; sB[1*E+e]=p1; sB[2*E+e]=p2; sB[3*E+e]=p3; }
    __syncthreads();
    if (h == 0) {
        float bb = lb[e] + t3b[e];
        float t2be = t2b[e];
        float vj[RT] = {p0,p1,p2,p3};
        #pragma unroll
        for (int jj = 0; jj < RT; ++jj) {
            size_t off = ((size_t)(b*NN + j0 + jj))*E + e;
            float v = vj[jj] + sB[jj*E+e] + bb;
            s13g[off] = v;
            mu0[off]  = fmaxf(v + t2be, 0.f);
        }
    }
}

// ============ iteration: mu_out = relu(s13 + (conn@mu_in)@t2w + t2b) ====
__global__ __launch_bounds__(256, 4) void k_iter(
    const float* __restrict__ Ws, const float* __restrict__ mi,
    const float* __restrict__ t2w, const float* __restrict__ t2b,
    const float* __restrict__ s13g, float* __restrict__ mo,
    float* __restrict__ poolbuf, int do_pool)
{
    const int blk = blockIdx.x;
    const int b   = blk >> 6;
    const int j0  = (blk & 63) * RT;
    const int t   = threadIdx.x;
    const int e   = t & (E-1);
    const int h   = t >> 7;

    __shared__ float sA[NN*RT];    // conn [i][jj]
    __shared__ float sB[RT*E];     // h1 partials [jj][e]
    __shared__ float sC[2*E*RT];   // C partials [h][k][jj]

    const float* wbase = Ws + (size_t)b*NN*NN;

    {   // stage conn: sA[i][jj] = (Ws[b, j0+jj, i] > 0); i = t, coalesced loads
        #pragma unroll
        for (int jj = 0; jj < RT; ++jj)
            sA[t*4 + jj] = (wbase[(size_t)(j0+jj)*NN + t] > 0.f) ? 1.f : 0.f;
    }
    __syncthreads();

    // C[jj][e] partial over i-half
    float a0=0,a1=0,a2=0,a3=0;
    {
        const float* mb = mi + ((size_t)b*NN + h*128)*E + e;
        const float* cb = sA + h*128*4;
        #pragma unroll 4
        for (int i = 0; i < 128; ++i) {
            float mv = mb[(size_t)i*E];          // coalesced (64 x 4B)
            f4 c = *(const f4*)(cb + i*4);       // broadcast
            a0 += c.x*mv; a1 += c.y*mv; a2 += c.z*mv; a3 += c.w*mv;
        }
    }
    *(f4*)(sC + (h*E + e)*4) = (f4){a0,a1,a2,a3};
    __syncthreads();

    // @t2w partial over k-half
    float o0=0,o1=0,o2=0,o3=0;
    #pragma unroll 4
    for (int k = h*64; k < h*64+64; ++k) {
        float w = t2w[k*E+e];
        f4 c0 = *(const f4*)(sC + k*4);
        f4 c1 = *(const f4*)(sC + (E+k)*4);
        o0 += (c0.x+c1.x)*w; o1 += (c0.y+c1.y)*w;
        o2 += (c0.z+c1.z)*w; o3 += (c0.w+c1.w)*w;
    }
    if (h == 1) { sB[0*E+e]=o0; sB[1*E+e]=o1; sB[2*E+e]=o2; sB[3*E+e]=o3; }
    __syncthreads();
    if (h == 0) {
        float t2be = t2b[e];
        size_t ro = ((size_t)(b*NN + j0))*E + e;
        float v0 = fmaxf(o0 + sB[0*E+e] + s13g[ro      ] + t2be, 0.f);
        float v1 = fmaxf(o1 + sB[1*E+e] + s13g[ro +   E] + t2be, 0.f);
        float v2 = fmaxf(o2 + sB[2*E+e] + s13g[ro + 2*E] + t2be, 0.f);
        float v3 = fmaxf(o3 + sB[3*E+e] + s13g[ro + 3*E] + t2be, 0.f);
        mo[ro] = v0; mo[ro+E] = v1; mo[ro+2*E] = v2; mo[ro+3*E] = v3;
        if (do_pool) atomicAdd(&poolbuf[b*E + e], v0+v1+v2+v3);
    }
}

// ============ epilogue: gsum (redundant/block) + theta7 + theta5 ========
__global__ __launch_bounds__(256, 4) void k_out(
    const float* __restrict__ mu, const float* __restrict__ t7w,
    const float* __restrict__ t7b, const float* __restrict__ t6w,
    const float* __restrict__ t6b, const float* __restrict__ t5w,
    const float* __restrict__ t5b, const float* __restrict__ poolbuf,
    float* __restrict__ out)
{
    const int blk = blockIdx.x;
    const int b   = blk >> 6;
    const int j0  = (blk & 63) * RT;
    const int t   = threadIdx.x;
    const int e   = t & (E-1);
    const int h   = t >> 7;

    __shared__ float mT[E*RT];     // mu rows transposed [k][jj]
    __shared__ float sG[2*E];      // t6 partials
    __shared__ float sB[RT*E];     // t7 h1 partials (f4 per e)
    __shared__ float sred[2*RT+2];

    // stage mu rows (coalesced over e)
    mT[e*4 + h]     = mu[((size_t)(b*NN + j0 + h))*E + e];
    mT[e*4 + 2 + h] = mu[((size_t)(b*NN + j0 + 2 + h))*E + e];

    // t6 partial over k-half (pool values uniform per k -> scalar loads)
    float gp = 0.f;
    {
        const float* pb = poolbuf + b*E;
        #pragma unroll 4
        for (int k = h*64; k < h*64+64; ++k)
            gp += pb[k] * t6w[k*E+e];
    }
    sG[h*E + e] = gp;
    __syncthreads();

    if (h == 0) {   // finish gsum: relu(pool@t6w + t6b) . t5w[0:E]
        float g = sG[e] + sG[E+e] + t6b[e];
        float v = fmaxf(g, 0.f) * t5w[e];
        #pragma unroll
        for (int off = 32; off; off >>= 1) v += __shfl_down(v, off, 64);
        if ((t & 63) == 0) sred[2*RT + (t >> 6)] = v;
    }

    // theta7 partial over k-half
    float l0=0,l1=0,l2=0,l3=0;
    #pragma unroll 4
    for (int k = h*64; k < h*64+64; ++k) {
        float w7 = t7w[k*E+e];
        f4 m = *(const f4*)(mT + k*4);   // broadcast
        l0 += m.x*w7; l1 += m.y*w7; l2 += m.z*w7; l3 += m.w*w7;
    }
    __syncthreads();
    if (h == 1) *(f4*)(sB + e*4) = (f4){l0,l1,l2,l3};
    __syncthreads();
    if (h == 0) {
        f4 lo = *(const f4*)(sB + e*4);
        float b7 = t7b[e], w5 = t5w[E+e];
        float v0 = fmaxf(l0+lo.x+b7, 0.f)*w5;
        float v1 = fmaxf(l1+lo.y+b7, 0.f)*w5;
        float v2 = fmaxf(l2+lo.z+b7, 0.f)*w5;
        float v3 = fmaxf(l3+lo.w+b7, 0.f)*w5;
        #pragma unroll
        for (int off = 32; off; off >>= 1) {
            v0 += __shfl_down(v0, off, 64);
            v1 += __shfl_down(v1, off, 64);
            v2 += __shfl_down(v2, off, 64);
            v3 += __shfl_down(v3, off, 64);
        }
        if ((t & 63) == 0) {
            int w = t >> 6;
            sred[w*RT+0]=v0; sred[w*RT+1]=v1; sred[w*RT+2]=v2; sred[w*RT+3]=v3;
        }
    }
    __syncthreads();
    if (t < RT) {
        float gs = sred[2*RT] + sred[2*RT+1];
        out[(size_t)b*NN + j0 + t] = sred[t] + sred[RT+t] + gs + t5b[0];
    }
}

extern "C" void kernel_launch(void* const* d_in, const int* in_sizes, int n_in,
                              void* d_out, int out_size, void* d_ws, size_t ws_size,
                              hipStream_t stream) {
    const float* xv  = (const float*)d_in[0];
    const float* Ws  = (const float*)d_in[1];
    const float* t1w = (const float*)d_in[2];  const float* t1b = (const float*)d_in[3];
    const float* t2w = (const float*)d_in[4];  const float* t2b = (const float*)d_in[5];
    const float* t3w = (const float*)d_in[6];  const float* t3b = (const float*)d_in[7];
    const float* t4w = (const float*)d_in[8];  const float* t4b = (const float*)d_in[9];
    const float* t5w = (const float*)d_in[10]; const float* t5b = (const float*)d_in[11];
    const float* t6w = (const float*)d_in[12]; const float* t6b = (const float*)d_in[13];
    const float* t7w = (const float*)d_in[14]; const float* t7b = (const float*)d_in[15];
    const float* lw  = (const float*)d_in[16]; const float* lb  = (const float*)d_in[17];
    float* outp = (float*)d_out;

    float* ws = (float*)d_ws;
    const int RE = BATCH*NN*E;
    float* s13g    = ws;
    float* mu0     = ws + RE;
    float* mu1     = ws + 2*RE;
    float* poolbuf = ws + 3*RE;

    const int GRID = BATCH * (NN/RT);   // 1024 blocks, 4 blocks/CU

    k_phase1<<<GRID, 256, 0, stream>>>(xv, Ws, t1w, t1b, t4w, t4b, t3w, t3b,
                                       lw, lb, t2b, s13g, mu0, poolbuf);
    k_iter<<<GRID, 256, 0, stream>>>(Ws, mu0, t2w, t2b, s13g, mu1, poolbuf, 0);
    k_iter<<<GRID, 256, 0, stream>>>(Ws, mu1, t2w, t2b, s13g, mu0, poolbuf, 0);
    k_iter<<<GRID, 256, 0, stream>>>(Ws, mu0, t2w, t2b, s13g, mu1, poolbuf, 1);
    k_out<<<GRID, 256, 0, stream>>>(mu1, t7w, t7b, t6w, t6b, t5w, t5b,
                                    poolbuf, outp);
}